// Round 10
// baseline (1502.601 us; speedup 1.0000x reference)
//
#include <hip/hip_runtime.h>
#include <hip/hip_bf16.h>

// SNN forward, MI355X (gfx950). Round 10: conv2 i8 at 2 blocks/CU (4 waves/SIMD)
// -- LDS cut to 50.8 KB (per-tap W2 dbuf staging via global_load_lds, tt=2 byte
// tiles), VGPR capped <=128 via waves_per_eu(4). Diagnosis r9: wall 20K cy/pass vs
// 11.7K MFMA demand = dependency latency at 2 waves/SIMD; buy concurrency.
//  - TAU1 == 1.0  =>  layer-1 stateless: s1 = (a1 >= TH1)  (binary)
//  - conv2 fused over all 20 timesteps: v2 state + spike counts in VGPRs.
//  - integer dot exact; only error source is W2 quantization (~1e-4 abs).

#define NB    64
#define NCIN  12
#define NC1   128
#define NC2   256
#define NT    20
#define NL    2048
#define GAINF 3.0f
#define THF   0.02f
#define W2SCALE 4310.0f

#define BROWS2 136
#define BSZ2   (BROWS2 * 128)   // 17408 B per-timestep byte tile (l-tile 128 + 8 halo)

typedef __bf16 bf16x8 __attribute__((ext_vector_type(8)));
typedef float  f32x4  __attribute__((ext_vector_type(4)));
typedef int    i32x4  __attribute__((ext_vector_type(4)));

__device__ __forceinline__ unsigned short f2bf(float f) {
  __hip_bfloat16 h = __float2bfloat16(f);
  return __builtin_bit_cast(unsigned short, h);
}

// ---------------- setup:
//  w1t: [c1][kd(128 zero-padded)] bf16
//  w2q: [tap][c2q][ (c2l*128 + c1) ^ ((c2l&7)<<4) ] int8 (c2 = c2q*64+c2l), pre-swizzled
//  s1p guard rows (l=-4..-1, 2048..2051 per (b,t)) zeroed
__global__ void snn_wsetup_kernel(const float* __restrict__ W1, const float* __restrict__ W2,
                                  unsigned short* __restrict__ w1t, unsigned char* __restrict__ w2q,
                                  unsigned char* __restrict__ s1p) {
  int idx = blockIdx.x * 256 + threadIdx.x;
  if (idx < 9 * 256 * 128) {
    int c1 = idx & 127;
    int c2 = (idx >> 7) & 255;
    int k  = idx >> 15;
    int c2q = c2 >> 6, c2l = c2 & 63;
    int dst = k * 32768 + c2q * 8192 + (((c2l * 128 + c1)) ^ ((c2l & 7) << 4));
    int q = __float2int_rn(W2[((size_t)c2 * 128 + c1) * 9 + k] * W2SCALE);
    w2q[dst] = (unsigned char)(signed char)q;
  }
  if (idx < 128 * 128) {
    int c1 = idx >> 7, kd = idx & 127;
    float v = 0.f;
    if (kd < 108) {
      int cin = kd / 9, kk = kd - cin * 9;
      v = W1[((size_t)c1 * 12 + cin) * 9 + kk];
    }
    w1t[idx] = f2bf(v);
  }
  if (idx < NB * NT * 8) {
    int bt = idx >> 3, r8 = idx & 7;
    size_t row = (size_t)bt * 2056 + (r8 < 4 ? r8 : 2048 + r8);  // 0..3, 2052..2055
    *(uint4*)(s1p + row * 16) = make_uint4(0u, 0u, 0u, 0u);
  }
}

// ---------------- conv1 + threshold (r7 proven version): one (b, l-tile, t) per block.
// s1p row layout: [b*20+t][2056 rows][16 B], row l at index l+4.
__global__ __launch_bounds__(256, 2) void snn_conv1_kernel(
    const float* __restrict__ x, const float* __restrict__ b1,
    const unsigned short* __restrict__ w1t, unsigned char* __restrict__ s1p) {
  __shared__ alignas(16) unsigned short ldsB[128 * 128];  // im2col [n][kd] swizzled
  __shared__ alignas(16) unsigned short ldsA[128 * 128];  // W1T [c1][kd] swizzled
  __shared__ float b1s[128];

  const int tid  = threadIdx.x;
  const int lane = tid & 63;
  const int wv   = tid >> 6;
  const int wm   = wv >> 1, wn = wv & 1;
  const int hi   = lane >> 4, lo = lane & 15;
  const int bid  = blockIdx.x;
  const int t    = bid % 20;
  const int r    = bid / 20;
  const int l0   = (r & 15) << 7;
  const int b    = r >> 4;

  {
    const uint4* gA = (const uint4*)w1t;
#pragma unroll
    for (int i = 0; i < 8; ++i) {
      int idx = tid + i * 256;
      unsigned off = (unsigned)idx * 16u;
      unsigned row = off >> 8;
      *(uint4*)((char*)ldsA + (off ^ ((row & 7u) << 4))) = gA[idx];
    }
  }
  if (tid < 128) b1s[tid] = b1[tid];

  for (int i = tid; i < 128 * 20; i += 256) {
    int n = i / 20, c = 108 + (i - n * 20);
    *(unsigned short*)((char*)ldsB + ((unsigned)(n * 256) + (((unsigned)c * 2u) ^ (((unsigned)n & 7u) << 4)))) = 0;
  }
  for (int e = tid; e < NCIN * 136; e += 256) {
    int cin = e / 136, i = e - cin * 136;
    int l = l0 - 4 + i;
    float xv = 0.f;
    if (l >= 0 && l < NL) xv = x[(((size_t)b * NCIN + cin) * NL + l) * NT + t];
    unsigned short hv = f2bf(xv);
    int kd0 = cin * 9;
#pragma unroll
    for (int k = 0; k < 9; ++k) {
      int n = i - k;
      if (n >= 0 && n < 128) {
        *(unsigned short*)((char*)ldsB + ((unsigned)(n * 256) + (((unsigned)(kd0 + k) * 2u) ^ (((unsigned)n & 7u) << 4)))) = hv;
      }
    }
  }
  __syncthreads();

  f32x4 acc[4][4];
#pragma unroll
  for (int mf = 0; mf < 4; ++mf)
#pragma unroll
    for (int nf = 0; nf < 4; ++nf) acc[mf][nf] = (f32x4){0.f, 0.f, 0.f, 0.f};

#pragma unroll
  for (int chunk = 0; chunk < 4; ++chunk) {
    const unsigned kd2 = (unsigned)(chunk * 32 + hi * 8) * 2u;
    bf16x8 af[4], bfr[4];
#pragma unroll
    for (int mf = 0; mf < 4; ++mf) {
      int rr = wm * 64 + mf * 16 + lo;
      af[mf] = *(const bf16x8*)((const char*)ldsA + ((unsigned)(rr * 256) + (kd2 ^ (((unsigned)rr & 7u) << 4))));
    }
#pragma unroll
    for (int nf = 0; nf < 4; ++nf) {
      int rr = wn * 64 + nf * 16 + lo;
      bfr[nf] = *(const bf16x8*)((const char*)ldsB + ((unsigned)(rr * 256) + (kd2 ^ (((unsigned)rr & 7u) << 4))));
    }
#pragma unroll
    for (int mf = 0; mf < 4; ++mf)
#pragma unroll
      for (int nf = 0; nf < 4; ++nf)
        acc[mf][nf] = __builtin_amdgcn_mfma_f32_16x16x32_bf16(af[mf], bfr[nf], acc[mf][nf], 0, 0, 0);
  }
  __syncthreads();

  // pack spikes: bit p of byte [l][jb] = spike(c1 = jb*8+p)
  unsigned char* ldsP = (unsigned char*)ldsB;
#pragma unroll
  for (int mf = 0; mf < 4; ++mf) {
    int c1b = wm * 64 + mf * 16 + hi * 4;
#pragma unroll
    for (int nf = 0; nf < 4; ++nf) {
      int lrow = wn * 64 + nf * 16 + lo;
      unsigned n4 = 0;
      n4 |= (GAINF * (acc[mf][nf][0] + b1s[c1b + 0]) >= THF) ? 1u : 0u;
      n4 |= (GAINF * (acc[mf][nf][1] + b1s[c1b + 1]) >= THF) ? 2u : 0u;
      n4 |= (GAINF * (acc[mf][nf][2] + b1s[c1b + 2]) >= THF) ? 4u : 0u;
      n4 |= (GAINF * (acc[mf][nf][3] + b1s[c1b + 3]) >= THF) ? 8u : 0u;
      unsigned p = (unsigned)__shfl_xor((int)n4, 16);  // partner hi^1
      if ((hi & 1) == 0) {
        ldsP[lrow * 16 + (wm * 8 + mf * 2 + (hi >> 1))] = (unsigned char)(n4 | (p << 4));
      }
    }
  }
  __syncthreads();

  if (tid < 128) {
    uint4 v = *(const uint4*)(ldsP + tid * 16);
    *(uint4*)(s1p + ((size_t)(b * 20 + t) * 2056 + 4 + l0 + tid) * 16) = v;
  }
}

// expand one 8-byte unit of spike bits (64 c1 values) into 64 i8 bytes in LDS row n.
__device__ __forceinline__ void expand_store(unsigned char* buf, int n, int h, uint2 bits) {
  unsigned swz = (unsigned)(n & 7) << 4;
  char* rowp = (char*)buf + n * 128;
#pragma unroll
  for (int q = 0; q < 4; ++q) {
    unsigned src = (q < 2) ? bits.x : bits.y;
    int sh = (q & 1) * 16;
    uint4 w;
    w.x = (((src >> (sh + 0)) & 15u) * 0x204081u) & 0x01010101u;
    w.y = (((src >> (sh + 4)) & 15u) * 0x204081u) & 0x01010101u;
    w.z = (((src >> (sh + 8)) & 15u) * 0x204081u) & 0x01010101u;
    w.w = (((src >> (sh + 12)) & 15u) * 0x204081u) & 0x01010101u;
    *(uint4*)(rowp + (((unsigned)(h * 64 + q * 16)) ^ swz)) = w;
  }
}

// ---------------- conv2 (i8) + LIF2 fused over all t, 2 timesteps per pass.
// block = (b, c2q of 64, l-tile of 128); 8 waves; wave = 64c2 x 16l x 2t.
// W2 staged per-tap (glds dbuf, 16 KB); spike bytes for 2 t in LDS (34.8 KB).
// LDS 50.8 KB + VGPR<=128 -> 2 blocks/CU = 4 waves/SIMD (the r10 lever).
__global__ __attribute__((amdgpu_flat_work_group_size(512, 512), amdgpu_waves_per_eu(4)))
void snn_conv2_kernel(const unsigned char* __restrict__ s1p, const unsigned char* __restrict__ w2q,
                      const float* __restrict__ b2, float* __restrict__ counts) {
  __shared__ alignas(16) unsigned char ldsW[2 * 8192];   // W2 tap double-buffer (swizzled content)
  __shared__ alignas(16) unsigned char ldsBy[2 * BSZ2];  // 34816 B: [tt][136 rows][128 B]

  const int tid  = threadIdx.x;
  const int lane = tid & 63;
  const int wv   = tid >> 6;       // 0..7 : l 16-block
  const int hi   = lane >> 4, lo = lane & 15;
  const int bid  = blockIdx.x;
  const int b    = bid >> 6;
  const int c2q  = (bid >> 4) & 3;
  const int l0   = (bid & 15) << 7;

  float gb2[4][4];
#pragma unroll
  for (int mf = 0; mf < 4; ++mf)
#pragma unroll
    for (int j = 0; j < 4; ++j)
      gb2[mf][j] = GAINF * b2[c2q * 64 + mf * 16 + hi * 4 + j];

  f32x4 v2s[4];
  int cnt[4][4];
#pragma unroll
  for (int mf = 0; mf < 4; ++mf) {
    v2s[mf] = (f32x4){0.f, 0.f, 0.f, 0.f};
#pragma unroll
    for (int j = 0; j < 4; ++j) cnt[mf][j] = 0;
  }

  // bits prefetch for pass ts=0: 544 x 8B units (2 t x 272); unit u: tt=u>=272, r=u-272*tt
  uint2 pA, pB = make_uint2(0u, 0u);
  {
    pA = *(const uint2*)(s1p + ((size_t)(b * 20 + (tid >= 272)) * 2056 + l0 +
                                ((tid >= 272 ? tid - 272 : tid) >> 1)) * 16 + (tid & 1) * 8);
    if (tid < 32) {
      int u = 512 + tid;  // 512..543 -> tt=1, r=240..271
      pB = *(const uint2*)(s1p + ((size_t)(b * 20 + 1) * 2056 + l0 + ((u - 272) >> 1)) * 16 + (u & 1) * 8);
    }
  }

  // prologue: stage tap 0 into buf 0 (drained by the first expand barrier)
  __builtin_amdgcn_global_load_lds(
      (const __attribute__((address_space(1))) void*)(w2q + (size_t)c2q * 8192 + wv * 1024 + lane * 16),
      (__attribute__((address_space(3))) void*)(ldsW + wv * 1024), 16, 0, 0);
  int cur = 0;

  const float it2 = 1.0f / 0.9f;
  const float isc = GAINF / W2SCALE;

  for (int ts = 0; ts < 20; ts += 2) {
    // expand bits -> bytes for the 2 timesteps of this pass
    {
      int tt = (tid >= 272), r = tid - 272 * tt;
      expand_store(ldsBy + tt * BSZ2, r >> 1, tid & 1, pA);
      if (tid < 32) expand_store(ldsBy + BSZ2, (512 + tid - 272) >> 1, tid & 1, pB);
    }
    __syncthreads();  // publish byte tiles; drains pending W2 tap stage (vmcnt0 before barrier)

    // prefetch bits for ts+2 (fly under the MFMA phase)
    if (ts < 18) {
      pA = *(const uint2*)(s1p + ((size_t)(b * 20 + ts + 2 + (tid >= 272)) * 2056 + l0 +
                                  ((tid >= 272 ? tid - 272 : tid) >> 1)) * 16 + (tid & 1) * 8);
      if (tid < 32) {
        int u = 512 + tid;
        pB = *(const uint2*)(s1p + ((size_t)(b * 20 + ts + 3) * 2056 + l0 + ((u - 272) >> 1)) * 16 + (u & 1) * 8);
      }
    }

    i32x4 acc[4][2];  // [mf][tt]
#pragma unroll
    for (int mf = 0; mf < 4; ++mf)
#pragma unroll
      for (int tt = 0; tt < 2; ++tt) acc[mf][tt] = (i32x4){0, 0, 0, 0};

#pragma unroll
    for (int tap = 0; tap < 9; ++tap) {
      // stage next tap into the other buffer (wraps to tap 0 for the next pass);
      // flies across this tap's MFMAs, drained at the barrier below.
      {
        int tapn = (tap == 8) ? 0 : tap + 1;
        __builtin_amdgcn_global_load_lds(
            (const __attribute__((address_space(1))) void*)(w2q + (size_t)tapn * 32768 + (size_t)c2q * 8192 + wv * 1024 + lane * 16),
            (__attribute__((address_space(3))) void*)(ldsW + ((cur ^ 1) << 13) + wv * 1024), 16, 0, 0);
      }
      const unsigned char* wbuf = ldsW + (cur << 13);
      __builtin_amdgcn_s_setprio(1);
#pragma unroll
      for (int chunk = 0; chunk < 2; ++chunk) {
        const unsigned ksl = (unsigned)(chunk * 64 + hi * 16);
        i32x4 af[4], bfr[2];
#pragma unroll
        for (int mf = 0; mf < 4; ++mf) {
          int rr = mf * 16 + lo;
          af[mf] = *(const i32x4*)(wbuf + (unsigned)(rr * 128) + (ksl ^ (((unsigned)rr & 7u) << 4)));
        }
        {
          int rs = wv * 16 + lo + tap;  // byte-tile row (l = l0-4+rs)
          unsigned off = (unsigned)(rs * 128) + (ksl ^ (((unsigned)rs & 7u) << 4));
          bfr[0] = *(const i32x4*)(ldsBy + off);
          bfr[1] = *(const i32x4*)(ldsBy + BSZ2 + off);
        }
#pragma unroll
        for (int mf = 0; mf < 4; ++mf)
#pragma unroll
          for (int tt = 0; tt < 2; ++tt)
            acc[mf][tt] = __builtin_amdgcn_mfma_i32_16x16x64_i8(af[mf], bfr[tt], acc[mf][tt], 0, 0, 0);
      }
      __builtin_amdgcn_s_setprio(0);
      __syncthreads();  // drains next-tap stage (vmcnt0); all waves done with ldsW[cur]
      cur ^= 1;
    }
    // (tap-8 barrier also guarantees all ldsBy reads of this pass are done)

    // LIF2: tt = ts, ts+1 sequential, pure register ops
#pragma unroll
    for (int tt = 0; tt < 2; ++tt) {
#pragma unroll
      for (int mf = 0; mf < 4; ++mf) {
#pragma unroll
        for (int j = 0; j < 4; ++j) {
          float a2 = (float)acc[mf][tt][j] * isc + gb2[mf][j];
          float vo = v2s[mf][j];
          float vn = vo + (a2 - vo) * it2;
          int sp2 = (vn >= THF) ? 1 : 0;
          v2s[mf][j] = sp2 ? 0.f : vn;
          cnt[mf][j] += sp2;
        }
      }
    }
  }

  // reduce counts over lo lanes (l within fragment), one atomic per (hi,mf,j)
#pragma unroll
  for (int mf = 0; mf < 4; ++mf)
#pragma unroll
    for (int j = 0; j < 4; ++j) {
      int c = cnt[mf][j];
      c += __shfl_xor(c, 1);
      c += __shfl_xor(c, 2);
      c += __shfl_xor(c, 4);
      c += __shfl_xor(c, 8);
      if (lo == 0) {
        int c2g = c2q * 64 + mf * 16 + hi * 4 + j;
        atomicAdd(&counts[b * NC2 + c2g], (float)c);
      }
    }
}

// ---------------- final FC
__global__ void snn_fc_kernel(const float* __restrict__ counts, const float* __restrict__ Wfc,
                              const float* __restrict__ bfc, float* __restrict__ out) {
  int tid = threadIdx.x;  // 256 = 64 b x 4 cls
  int b = tid >> 2, cls = tid & 3;
  float s = 0.f;
  for (int c = 0; c < 256; ++c) s += counts[b * 256 + c] * Wfc[cls * 256 + c];
  out[tid] = s * (1.0f / ((float)NT * (float)NL)) + bfc[cls];
}

extern "C" void kernel_launch(void* const* d_in, const int* in_sizes, int n_in,
                              void* d_out, int out_size, void* d_ws, size_t ws_size,
                              hipStream_t stream) {
  const float* x   = (const float*)d_in[0];
  const float* W1  = (const float*)d_in[1];
  const float* b1  = (const float*)d_in[2];
  const float* W2  = (const float*)d_in[3];
  const float* b2  = (const float*)d_in[4];
  const float* Wfc = (const float*)d_in[5];
  const float* bfc = (const float*)d_in[6];
  float* out = (float*)d_out;
  char* ws = (char*)d_ws;

  const size_t SZ_S1P = (size_t)NB * NT * 2056 * 16;   // 42,106,880 (bitpacked s1 + guards)
  const size_t SZ_W2Q = (size_t)9 * 256 * 128;         // 294,912 (int8, pre-swizzled)
  const size_t SZ_W1T = (size_t)128 * 128 * 2;         // 32,768
  const size_t SZ_CNT = (size_t)NB * NC2 * 4;          // 65,536

  const size_t OFF_S1P = 0;
  const size_t OFF_W2Q = OFF_S1P + SZ_S1P;
  const size_t OFF_W1T = OFF_W2Q + SZ_W2Q;
  const size_t OFF_CNT = OFF_W1T + SZ_W1T;
  const size_t NEEDED  = OFF_CNT + SZ_CNT;
  if (ws_size < NEEDED) return;

  unsigned char*  s1p = (unsigned char*)(ws + OFF_S1P);
  unsigned char*  w2q = (unsigned char*)(ws + OFF_W2Q);
  unsigned short* w1t = (unsigned short*)(ws + OFF_W1T);
  float* counts = (float*)(ws + OFF_CNT);

  hipMemsetAsync(counts, 0, SZ_CNT, stream);
  snn_wsetup_kernel<<<1152, 256, 0, stream>>>(W1, W2, w1t, w2q, s1p);
  snn_conv1_kernel<<<NB * 16 * NT, 256, 0, stream>>>(x, b1, w1t, s1p);
  snn_conv2_kernel<<<NB * 4 * 16, 512, 0, stream>>>(s1p, w2q, b2, counts);
  snn_fc_kernel<<<1, 256, 0, stream>>>(counts, Wfc, bfc, out);
}

// Round 11
// 834.686 us; speedup vs baseline: 1.8002x; 1.8002x over previous
//
#include <hip/hip_runtime.h>
#include <hip/hip_bf16.h>

// SNN forward, MI355X (gfx950). Round 11: conv2 restored to the proven r7 version
// (668us: W2 all-taps LDS-resident, 2-t batched byte tiles, wave 64c2x32lx2t);
// conv1 batched 4 timesteps per block (x staged once as coalesced float4 -> bf16,
// W1 staged once, 4x less line amplification and W1-restaging).
//  - TAU1 == 1.0  =>  layer-1 stateless: s1 = (a1 >= TH1)  (binary)
//  - conv2 fused over all 20 timesteps: v2 state + spike counts in VGPRs.
//  - integer dot exact; only error source is W2 quantization (~1e-4 abs).

#define NB    64
#define NCIN  12
#define NC1   128
#define NC2   256
#define NT    20
#define NL    2048
#define GAINF 3.0f
#define THF   0.02f
#define W2SCALE 4310.0f

#define BROWS 264
#define BSZ   (BROWS * 128)   // 33792 B per timestep byte-tile

typedef __bf16 bf16x8 __attribute__((ext_vector_type(8)));
typedef float  f32x4  __attribute__((ext_vector_type(4)));
typedef int    i32x4  __attribute__((ext_vector_type(4)));

__device__ __forceinline__ unsigned short f2bf(float f) {
  __hip_bfloat16 h = __float2bfloat16(f);
  return __builtin_bit_cast(unsigned short, h);
}

// ---------------- setup:
//  w1t: [c1][kd(128 zero-padded)] bf16
//  w2q: [tap][c2q][ (c2l*128 + c1) ^ ((c2l&7)<<4) ] int8 (c2 = c2q*64+c2l), pre-swizzled
//  s1p guard rows (l=-4..-1, 2048..2051 per (b,t)) zeroed
__global__ void snn_wsetup_kernel(const float* __restrict__ W1, const float* __restrict__ W2,
                                  unsigned short* __restrict__ w1t, unsigned char* __restrict__ w2q,
                                  unsigned char* __restrict__ s1p) {
  int idx = blockIdx.x * 256 + threadIdx.x;
  if (idx < 9 * 256 * 128) {
    int c1 = idx & 127;
    int c2 = (idx >> 7) & 255;
    int k  = idx >> 15;
    int c2q = c2 >> 6, c2l = c2 & 63;
    int dst = k * 32768 + c2q * 8192 + (((c2l * 128 + c1)) ^ ((c2l & 7) << 4));
    int q = __float2int_rn(W2[((size_t)c2 * 128 + c1) * 9 + k] * W2SCALE);
    w2q[dst] = (unsigned char)(signed char)q;
  }
  if (idx < 128 * 128) {
    int c1 = idx >> 7, kd = idx & 127;
    float v = 0.f;
    if (kd < 108) {
      int cin = kd / 9, kk = kd - cin * 9;
      v = W1[((size_t)c1 * 12 + cin) * 9 + kk];
    }
    w1t[idx] = f2bf(v);
  }
  if (idx < NB * NT * 8) {
    int bt = idx >> 3, r8 = idx & 7;
    size_t row = (size_t)bt * 2056 + (r8 < 4 ? r8 : 2048 + r8);  // 0..3, 2052..2055
    *(uint4*)(s1p + row * 16) = make_uint4(0u, 0u, 0u, 0u);
  }
}

// ---------------- conv1 + threshold, 4 timesteps per block: writes bitpacked s1.
// block = (b, l-tile of 128, t-group of 4). x tile staged ONCE as float4 (t-contiguous),
// W1 staged once; then 4 x { im2col build -> MFMA -> spike-pack -> copy-out }.
// s1p row layout: [b*20+t][2056 rows][16 B], row l at index l+4.
__global__ __launch_bounds__(256, 2) void snn_conv1_kernel(
    const float* __restrict__ x, const float* __restrict__ b1,
    const unsigned short* __restrict__ w1t, unsigned char* __restrict__ s1p) {
  __shared__ alignas(16) unsigned short ldsB[128 * 128];      // im2col [n][kd] swizzled (32 KB)
  __shared__ alignas(16) unsigned short ldsA[128 * 128];      // W1T [c1][kd] swizzled (32 KB)
  __shared__ alignas(16) unsigned short xt[NCIN * 136 * 4];   // x tile bf16, 4 t (13056 B)
  __shared__ alignas(16) unsigned char  ldsP[128 * 16];       // spike pack (2 KB)
  __shared__ float b1s[128];

  const int tid  = threadIdx.x;
  const int lane = tid & 63;
  const int wv   = tid >> 6;
  const int wm   = wv >> 1, wn = wv & 1;
  const int hi   = lane >> 4, lo = lane & 15;
  const int bid  = blockIdx.x;
  const int tg   = bid % 5;            // t = tg*4 + tt
  const int r    = bid / 5;
  const int l0   = (r & 15) << 7;
  const int b    = r >> 4;

  // stage W1T swizzled
  {
    const uint4* gA = (const uint4*)w1t;
#pragma unroll
    for (int i = 0; i < 8; ++i) {
      int idx = tid + i * 256;
      unsigned off = (unsigned)idx * 16u;
      unsigned row = off >> 8;
      *(uint4*)((char*)ldsA + (off ^ ((row & 7u) << 4))) = gA[idx];
    }
  }
  if (tid < 128) b1s[tid] = b1[tid];

  // zero im2col cols 108..127 once (A is zero there, but avoid NaN garbage in B)
  for (int i = tid; i < 128 * 20; i += 256) {
    int n = i / 20, c = 108 + (i - n * 20);
    *(unsigned short*)((char*)ldsB + ((unsigned)(n * 256) + (((unsigned)c * 2u) ^ (((unsigned)n & 7u) << 4)))) = 0;
  }

  // stage x tile: unit (cin, ll) reads float4 of 4 t (16B-aligned: l*20 + tg*4 is mult of 4)
#pragma unroll
  for (int k = 0; k < 7; ++k) {
    int u = tid + k * 256;
    if (u < NCIN * 136) {
      int cin = u / 136, ll = u - cin * 136;
      int l = l0 - 4 + ll;
      float4 f = make_float4(0.f, 0.f, 0.f, 0.f);
      if (l >= 0 && l < NL)
        f = *(const float4*)(x + (((size_t)b * NCIN + cin) * NL + l) * NT + tg * 4);
      uint2 w;
      w.x = (unsigned)f2bf(f.x) | ((unsigned)f2bf(f.y) << 16);
      w.y = (unsigned)f2bf(f.z) | ((unsigned)f2bf(f.w) << 16);
      *(uint2*)&xt[u * 4] = w;
    }
  }
  __syncthreads();

  for (int tt = 0; tt < 4; ++tt) {
    // build im2col from xt (LDS->LDS)
#pragma unroll
    for (int k = 0; k < 7; ++k) {
      int e = tid + k * 256;
      if (e < NCIN * 136) {
        int cin = e / 136, i = e - cin * 136;
        unsigned short hv = xt[e * 4 + tt];
        int kd0 = cin * 9;
#pragma unroll
        for (int kk = 0; kk < 9; ++kk) {
          int n = i - kk;
          if (n >= 0 && n < 128) {
            *(unsigned short*)((char*)ldsB + ((unsigned)(n * 256) + (((unsigned)(kd0 + kk) * 2u) ^ (((unsigned)n & 7u) << 4)))) = hv;
          }
        }
      }
    }
    __syncthreads();

    f32x4 acc[4][4];
#pragma unroll
    for (int mf = 0; mf < 4; ++mf)
#pragma unroll
      for (int nf = 0; nf < 4; ++nf) acc[mf][nf] = (f32x4){0.f, 0.f, 0.f, 0.f};

#pragma unroll
    for (int chunk = 0; chunk < 4; ++chunk) {
      const unsigned kd2 = (unsigned)(chunk * 32 + hi * 8) * 2u;
      bf16x8 af[4], bfr[4];
#pragma unroll
      for (int mf = 0; mf < 4; ++mf) {
        int rr = wm * 64 + mf * 16 + lo;
        af[mf] = *(const bf16x8*)((const char*)ldsA + ((unsigned)(rr * 256) + (kd2 ^ (((unsigned)rr & 7u) << 4))));
      }
#pragma unroll
      for (int nf = 0; nf < 4; ++nf) {
        int rr = wn * 64 + nf * 16 + lo;
        bfr[nf] = *(const bf16x8*)((const char*)ldsB + ((unsigned)(rr * 256) + (kd2 ^ (((unsigned)rr & 7u) << 4))));
      }
#pragma unroll
      for (int mf = 0; mf < 4; ++mf)
#pragma unroll
        for (int nf = 0; nf < 4; ++nf)
          acc[mf][nf] = __builtin_amdgcn_mfma_f32_16x16x32_bf16(af[mf], bfr[nf], acc[mf][nf], 0, 0, 0);
    }

    // pack spikes: bit p of byte [l][jb] = spike(c1 = jb*8+p)
#pragma unroll
    for (int mf = 0; mf < 4; ++mf) {
      int c1b = wm * 64 + mf * 16 + hi * 4;
#pragma unroll
      for (int nf = 0; nf < 4; ++nf) {
        int lrow = wn * 64 + nf * 16 + lo;
        unsigned n4 = 0;
        n4 |= (GAINF * (acc[mf][nf][0] + b1s[c1b + 0]) >= THF) ? 1u : 0u;
        n4 |= (GAINF * (acc[mf][nf][1] + b1s[c1b + 1]) >= THF) ? 2u : 0u;
        n4 |= (GAINF * (acc[mf][nf][2] + b1s[c1b + 2]) >= THF) ? 4u : 0u;
        n4 |= (GAINF * (acc[mf][nf][3] + b1s[c1b + 3]) >= THF) ? 8u : 0u;
        unsigned p = (unsigned)__shfl_xor((int)n4, 16);  // partner hi^1
        if ((hi & 1) == 0) {
          ldsP[lrow * 16 + (wm * 8 + mf * 2 + (hi >> 1))] = (unsigned char)(n4 | (p << 4));
        }
      }
    }
    __syncthreads();

    if (tid < 128) {
      uint4 v = *(const uint4*)(ldsP + tid * 16);
      *(uint4*)(s1p + ((size_t)(b * 20 + tg * 4 + tt) * 2056 + 4 + l0 + tid) * 16) = v;
    }
    // next build overwrites ldsB only after this barrier-pair; ldsP re-written only
    // after the next pack barrier -> no extra barrier needed here.
  }
}

// expand one 8-byte unit of spike bits (64 c1 values) into 64 i8 bytes in LDS row n.
__device__ __forceinline__ void expand_store(unsigned char* buf, int n, int h, uint2 bits) {
  unsigned swz = (unsigned)(n & 7) << 4;
  char* rowp = (char*)buf + n * 128;
#pragma unroll
  for (int q = 0; q < 4; ++q) {
    unsigned src = (q < 2) ? bits.x : bits.y;
    int sh = (q & 1) * 16;
    uint4 w;
    w.x = (((src >> (sh + 0)) & 15u) * 0x204081u) & 0x01010101u;
    w.y = (((src >> (sh + 4)) & 15u) * 0x204081u) & 0x01010101u;
    w.z = (((src >> (sh + 8)) & 15u) * 0x204081u) & 0x01010101u;
    w.w = (((src >> (sh + 12)) & 15u) * 0x204081u) & 0x01010101u;
    *(uint4*)(rowp + (((unsigned)(h * 64 + q * 16)) ^ swz)) = w;
  }
}

// ---------------- conv2 (i8) + LIF2 fused over all t, 2 timesteps per pass (r7 exact).
// block = (b, c2-quarter of 64, l-tile of 256); 8 waves; wave = 64c2 x 32l x 2t.
// W2 all 9 taps LDS-resident (72 KB); spike bytes for 2 t in LDS (67.5 KB).
__global__ __attribute__((amdgpu_flat_work_group_size(512, 512), amdgpu_waves_per_eu(2, 2)))
void snn_conv2_kernel(const unsigned char* __restrict__ s1p, const unsigned char* __restrict__ w2q,
                      const float* __restrict__ b2, float* __restrict__ counts) {
  __shared__ alignas(16) unsigned char ldsW[9 * 8192];   // 72 KB: [tap][64 c2 x 128 c1] swizzled
  __shared__ alignas(16) unsigned char ldsBy[2 * BSZ];   // 67.5 KB: [tt][264 rows][128 B]

  const int tid  = threadIdx.x;
  const int lane = tid & 63;
  const int wv   = tid >> 6;   // 0..7 : l 32-block
  const int hi   = lane >> 4, lo = lane & 15;
  const int bid  = blockIdx.x;
  const int b    = bid >> 5;
  const int r5b  = bid & 31;
  const int c2q  = r5b >> 3;
  const int l0   = (r5b & 7) << 8;

  // stage all 9 W2 tap tiles (8 KB each, pre-swizzled) into LDS, linear glds
#pragma unroll
  for (int tp = 0; tp < 9; ++tp) {
    __builtin_amdgcn_global_load_lds(
        (const __attribute__((address_space(1))) void*)(w2q + (size_t)tp * 32768 + (size_t)c2q * 8192 + wv * 1024 + lane * 16),
        (__attribute__((address_space(3))) void*)(ldsW + tp * 8192 + wv * 1024), 16, 0, 0);
  }

  float gb2[4][4];
#pragma unroll
  for (int mf = 0; mf < 4; ++mf)
#pragma unroll
    for (int j = 0; j < 4; ++j)
      gb2[mf][j] = GAINF * b2[c2q * 64 + mf * 16 + hi * 4 + j];

  f32x4 v2s[4][2];
  int cnt[4][4];
#pragma unroll
  for (int mf = 0; mf < 4; ++mf) {
#pragma unroll
    for (int nf = 0; nf < 2; ++nf) v2s[mf][nf] = (f32x4){0.f, 0.f, 0.f, 0.f};
#pragma unroll
    for (int j = 0; j < 4; ++j) cnt[mf][j] = 0;
  }

  // bits prefetch for ts=0 (1056 x 8B units over both tt; thread: tid, tid+512, [tid<32] tid+1024)
  uint2 pA, pB, pC = make_uint2(0u, 0u);
  {
    const unsigned char* spA = s1p + ((size_t)(b * 20 + 0) * 2056 + l0) * 16;
    const unsigned char* spB = s1p + ((size_t)(b * 20 + 1) * 2056 + l0) * 16;
    pA = *(const uint2*)(spA + (size_t)tid * 8);
    pB = (tid < 16) ? *(const uint2*)(spA + (size_t)(512 + tid) * 8)
                    : *(const uint2*)(spB + (size_t)(tid - 16) * 8);
    if (tid < 32) pC = *(const uint2*)(spB + (size_t)(496 + tid) * 8);
  }

  const float it2 = 1.0f / 0.9f;
  const float isc = GAINF / W2SCALE;

  for (int ts = 0; ts < 20; ts += 2) {
    // expand bits -> bytes for both timesteps of this pass
    expand_store(ldsBy, tid >> 1, tid & 1, pA);
    if (tid < 16) expand_store(ldsBy, 256 + (tid >> 1), tid & 1, pB);
    else          expand_store(ldsBy + BSZ, (tid - 16) >> 1, (tid - 16) & 1, pB);
    if (tid < 32) expand_store(ldsBy + BSZ, 248 + (tid >> 1), tid & 1, pC);
    __syncthreads();  // publish bytes (first iter: also drains W2 glds)

    // prefetch bits for ts+2 (fly under the MFMA phase)
    if (ts < 18) {
      const unsigned char* snA = s1p + ((size_t)(b * 20 + ts + 2) * 2056 + l0) * 16;
      const unsigned char* snB = s1p + ((size_t)(b * 20 + ts + 3) * 2056 + l0) * 16;
      pA = *(const uint2*)(snA + (size_t)tid * 8);
      pB = (tid < 16) ? *(const uint2*)(snA + (size_t)(512 + tid) * 8)
                      : *(const uint2*)(snB + (size_t)(tid - 16) * 8);
      if (tid < 32) pC = *(const uint2*)(snB + (size_t)(496 + tid) * 8);
    }

    i32x4 acc[4][2][2];  // [mf][tt][nf]
#pragma unroll
    for (int mf = 0; mf < 4; ++mf)
#pragma unroll
      for (int tt = 0; tt < 2; ++tt)
#pragma unroll
        for (int nf = 0; nf < 2; ++nf) acc[mf][tt][nf] = (i32x4){0, 0, 0, 0};

#pragma unroll
    for (int tap = 0; tap < 9; ++tap) {
#pragma unroll
      for (int chunk = 0; chunk < 2; ++chunk) {
        const unsigned ksl = (unsigned)(chunk * 64 + hi * 16);
        i32x4 af[4], bf[2][2];
#pragma unroll
        for (int mf = 0; mf < 4; ++mf) {
          int rr = mf * 16 + lo;
          unsigned off = (unsigned)(rr * 128) + (ksl ^ (((unsigned)rr & 7u) << 4));
          af[mf] = *(const i32x4*)(ldsW + tap * 8192 + off);
        }
#pragma unroll
        for (int nf = 0; nf < 2; ++nf) {
          int rs = wv * 32 + nf * 16 + lo + tap;  // byte-tile row (l = l0-4+rs)
          unsigned off = (unsigned)(rs * 128) + (ksl ^ (((unsigned)rs & 7u) << 4));
          bf[0][nf] = *(const i32x4*)(ldsBy + off);
          bf[1][nf] = *(const i32x4*)(ldsBy + BSZ + off);
        }
#pragma unroll
        for (int mf = 0; mf < 4; ++mf)
#pragma unroll
          for (int tt = 0; tt < 2; ++tt)
#pragma unroll
            for (int nf = 0; nf < 2; ++nf)
              acc[mf][tt][nf] = __builtin_amdgcn_mfma_i32_16x16x64_i8(af[mf], bf[tt][nf], acc[mf][tt][nf], 0, 0, 0);
      }
    }

    // LIF2: tt=0 then tt=1 (sequential in t), pure register ops
#pragma unroll
    for (int tt = 0; tt < 2; ++tt) {
#pragma unroll
      for (int mf = 0; mf < 4; ++mf) {
#pragma unroll
        for (int nf = 0; nf < 2; ++nf) {
#pragma unroll
          for (int j = 0; j < 4; ++j) {
            float a2 = (float)acc[mf][tt][nf][j] * isc + gb2[mf][j];
            float vo = v2s[mf][nf][j];
            float vn = vo + (a2 - vo) * it2;
            int sp2 = (vn >= THF) ? 1 : 0;
            v2s[mf][nf][j] = sp2 ? 0.f : vn;
            cnt[mf][j] += sp2;
          }
        }
      }
    }

    __syncthreads();  // all byte-tile reads done; next pass may overwrite
  }

  // reduce counts over lo lanes (l within fragment), one atomic per (hi,mf,j)
#pragma unroll
  for (int mf = 0; mf < 4; ++mf)
#pragma unroll
    for (int j = 0; j < 4; ++j) {
      int c = cnt[mf][j];
      c += __shfl_xor(c, 1);
      c += __shfl_xor(c, 2);
      c += __shfl_xor(c, 4);
      c += __shfl_xor(c, 8);
      if (lo == 0) {
        int c2g = c2q * 64 + mf * 16 + hi * 4 + j;
        atomicAdd(&counts[b * NC2 + c2g], (float)c);
      }
    }
}

// ---------------- final FC
__global__ void snn_fc_kernel(const float* __restrict__ counts, const float* __restrict__ Wfc,
                              const float* __restrict__ bfc, float* __restrict__ out) {
  int tid = threadIdx.x;  // 256 = 64 b x 4 cls
  int b = tid >> 2, cls = tid & 3;
  float s = 0.f;
  for (int c = 0; c < 256; ++c) s += counts[b * 256 + c] * Wfc[cls * 256 + c];
  out[tid] = s * (1.0f / ((float)NT * (float)NL)) + bfc[cls];
}

extern "C" void kernel_launch(void* const* d_in, const int* in_sizes, int n_in,
                              void* d_out, int out_size, void* d_ws, size_t ws_size,
                              hipStream_t stream) {
  const float* x   = (const float*)d_in[0];
  const float* W1  = (const float*)d_in[1];
  const float* b1  = (const float*)d_in[2];
  const float* W2  = (const float*)d_in[3];
  const float* b2  = (const float*)d_in[4];
  const float* Wfc = (const float*)d_in[5];
  const float* bfc = (const float*)d_in[6];
  float* out = (float*)d_out;
  char* ws = (char*)d_ws;

  const size_t SZ_S1P = (size_t)NB * NT * 2056 * 16;   // 42,106,880 (bitpacked s1 + guards)
  const size_t SZ_W2Q = (size_t)9 * 256 * 128;         // 294,912 (int8, pre-swizzled)
  const size_t SZ_W1T = (size_t)128 * 128 * 2;         // 32,768
  const size_t SZ_CNT = (size_t)NB * NC2 * 4;          // 65,536

  const size_t OFF_S1P = 0;
  const size_t OFF_W2Q = OFF_S1P + SZ_S1P;
  const size_t OFF_W1T = OFF_W2Q + SZ_W2Q;
  const size_t OFF_CNT = OFF_W1T + SZ_W1T;
  const size_t NEEDED  = OFF_CNT + SZ_CNT;
  if (ws_size < NEEDED) return;

  unsigned char*  s1p = (unsigned char*)(ws + OFF_S1P);
  unsigned char*  w2q = (unsigned char*)(ws + OFF_W2Q);
  unsigned short* w1t = (unsigned short*)(ws + OFF_W1T);
  float* counts = (float*)(ws + OFF_CNT);

  hipMemsetAsync(counts, 0, SZ_CNT, stream);
  snn_wsetup_kernel<<<1152, 256, 0, stream>>>(W1, W2, w1t, w2q, s1p);
  snn_conv1_kernel<<<NB * 16 * 5, 256, 0, stream>>>(x, b1, w1t, s1p);
  snn_conv2_kernel<<<NB * 4 * 8, 512, 0, stream>>>(s1p, w2q, b2, counts);
  snn_fc_kernel<<<1, 256, 0, stream>>>(counts, Wfc, bfc, out);
}